// Round 8
// baseline (80.848 us; speedup 1.0000x reference)
//
#include <hip/hip_runtime.h>

#define NB 8
#define TNEW 128
#define CMAX 2048
#define DMODEL 1024
#define NH 16
#define DH 64

typedef float f32x4 __attribute__((ext_vector_type(4)));
typedef short short8 __attribute__((ext_vector_type(8)));
typedef short short4v __attribute__((ext_vector_type(4)));

__device__ __forceinline__ short f2bf(float x) {
  unsigned u = __float_as_uint(x);
  u += 0x7FFFu + ((u >> 16) & 1u);   // RTNE
  return (short)(u >> 16);
}
__device__ __forceinline__ float bf2f(short s) {
  return __uint_as_float(((unsigned)(unsigned short)s) << 16);
}
__device__ __forceinline__ short8 cvt8(f32x4 a, f32x4 b) {
  short8 o;
  o[0] = f2bf(a.x); o[1] = f2bf(a.y); o[2] = f2bf(a.z); o[3] = f2bf(a.w);
  o[4] = f2bf(b.x); o[5] = f2bf(b.y); o[6] = f2bf(b.z); o[7] = f2bf(b.w);
  return o;
}

#define LGKM0_BAR()                                            \
  __builtin_amdgcn_sched_barrier(0);                           \
  asm volatile("s_waitcnt lgkmcnt(0)" ::: "memory");           \
  __builtin_amdgcn_sched_barrier(0);                           \
  __builtin_amdgcn_s_barrier()
#define TAIL_BAR()                                             \
  __builtin_amdgcn_sched_barrier(0);                           \
  __builtin_amdgcn_s_barrier()

// ---------------- fused f32 -> bf16 convert: x, Wq, Wk, Wv, Wo ----------------
__global__ __launch_bounds__(256) void cvt5_bf16(
    const float* __restrict__ s0, const float* __restrict__ s1,
    const float* __restrict__ s2, const float* __restrict__ s3,
    const float* __restrict__ s4, short* __restrict__ dst) {
  const int seg = blockIdx.x >> 10;
  const int i = (blockIdx.x & 1023) * 256 + threadIdx.x;
  const float* src = seg == 0 ? s0 : seg == 1 ? s1 : seg == 2 ? s2 : seg == 3 ? s3 : s4;
  f32x4 v = *(const f32x4*)(src + (size_t)i * 4);
  short4v o;
  o.x = f2bf(v.x); o.y = f2bf(v.y); o.z = f2bf(v.z); o.w = f2bf(v.w);
  *(short4v*)(dst + (size_t)seg * (1u << 20) + (size_t)i * 4) = o;
}

// ---------------- GEMM: C[r,n] = sum_m A[r,m] * W[n,m] (+bias) ----------------
// Raw-barrier software pipeline: loads for kt+1 stay in flight across barriers.
template<int MODE>
__global__ __launch_bounds__(256) void gemm64(
    const short* __restrict__ A, const short* __restrict__ Wbase,
    void* __restrict__ Out, const float* __restrict__ bias0,
    const float* __restrict__ bias1, const float* __restrict__ bias2,
    const int* __restrict__ new_len)
{
  constexpr int LDT = 40;
  __shared__ short As[64 * LDT];
  __shared__ short Bs[64 * LDT];
  const int n0 = blockIdx.x * 64, m0 = blockIdx.y * 64, z = blockIdx.z;
  // q/k/v rows t >= new_len[b] are never consumed (wave-skip in attn; j<total for k/v).
  if (MODE == 0 && (m0 & 64) && new_len[m0 >> 7] <= 64) return;
  const short* Wp = Wbase + (size_t)z * (DMODEL * DMODEL);
  const float* bias = (MODE == 0) ? (z == 0 ? bias0 : (z == 1 ? bias1 : bias2)) : bias0;
  const int tid = threadIdx.x, lane = tid & 63, w = tid >> 6;
  const int wm = (w >> 1) * 32, wn = (w & 1) * 32;
  const int lr = lane & 15, lk = lane >> 4;

  const int srow = tid >> 2, soff = (tid & 3) * 8;
  const short* Ag = A  + (size_t)(m0 + srow) * DMODEL + soff;
  const short* Bg = Wp + (size_t)(n0 + srow) * DMODEL + soff;
  short* Al = As + srow * LDT + soff;
  short* Bl = Bs + srow * LDT + soff;

  short8 va0 = *(const short8*)(Ag);
  short8 vb0 = *(const short8*)(Bg);
  short8 va1, vb1;
  f32x4 acc[2][2] = {};

#define GEMM_PHASE(CURA, CURB, NXTA, NXTB, KNEXT)                          \
  {                                                                        \
    *(short8*)Al = CURA;                                                   \
    *(short8*)Bl = CURB;                                                   \
    NXTA = *(const short8*)(Ag + (KNEXT) * 32);                            \
    NXTB = *(const short8*)(Bg + (KNEXT) * 32);                            \
    LGKM0_BAR();                                                           \
    short8 af0 = *(const short8*)(As + (wm + lr) * LDT + lk * 8);          \
    short8 af1 = *(const short8*)(As + (wm + 16 + lr) * LDT + lk * 8);     \
    short8 bg0 = *(const short8*)(Bs + (wn + lr) * LDT + lk * 8);          \
    short8 bg1 = *(const short8*)(Bs + (wn + 16 + lr) * LDT + lk * 8);     \
    acc[0][0] = __builtin_amdgcn_mfma_f32_16x16x32_bf16(af0, bg0, acc[0][0], 0, 0, 0); \
    acc[0][1] = __builtin_amdgcn_mfma_f32_16x16x32_bf16(af0, bg1, acc[0][1], 0, 0, 0); \
    acc[1][0] = __builtin_amdgcn_mfma_f32_16x16x32_bf16(af1, bg0, acc[1][0], 0, 0, 0); \
    acc[1][1] = __builtin_amdgcn_mfma_f32_16x16x32_bf16(af1, bg1, acc[1][1], 0, 0, 0); \
    TAIL_BAR();                                                            \
  }

  for (int kt = 0; kt < DMODEL / 32; kt += 2) {
    const int k1 = kt + 1;
    const int k2 = (kt + 2 < DMODEL / 32) ? kt + 2 : DMODEL / 32 - 1;  // clamped, unused on last
    GEMM_PHASE(va0, vb0, va1, vb1, k1);
    GEMM_PHASE(va1, vb1, va0, vb0, k2);
  }
#undef GEMM_PHASE

#pragma unroll
  for (int i = 0; i < 2; ++i) {
#pragma unroll
    for (int j = 0; j < 2; ++j) {
      const int col = n0 + wn + j * 16 + lr;
      const float bcol = bias[col];
#pragma unroll
      for (int r = 0; r < 4; ++r) {
        const int row = m0 + wm + i * 16 + lk * 4 + r;
        float v = acc[i][j][r] + bcol;
        if (MODE == 0) {
          ((short*)Out)[(size_t)z * (NB * TNEW * DMODEL) + (size_t)row * DMODEL + col] = f2bf(v);
        } else {
          const int bb = row >> 7, t = row & 127;
          ((float*)Out)[(size_t)row * DMODEL + col] = (t < new_len[bb]) ? v : 0.0f;
        }
      }
    }
  }
}

// ---------------- RoPE + validity masking on q,k (and v mask) ----------------
__global__ __launch_bounds__(256) void rope_mask(
    short* __restrict__ qb, short* __restrict__ kb, short* __restrict__ vb,
    const float* __restrict__ inv_freq, const int* __restrict__ past_len,
    const int* __restrict__ new_len)
{
  const int idx = blockIdx.x * 256 + threadIdx.x;  // B*T*H*32 = 524288
  const int d = idx & 31;
  const int h = (idx >> 5) & 15;
  const int t = (idx >> 9) & 127;
  const int b = idx >> 16;
  const bool valid = t < new_len[b];
  const float pos = (float)(past_len[b] + t);
  float sn, cs;
  sincosf(pos * inv_freq[d], &sn, &cs);
  const size_t base = (size_t)(b * 128 + t) * DMODEL + h * 64 + d;
  const float q1 = bf2f(qb[base]), q2 = bf2f(qb[base + 32]);
  const float k1 = bf2f(kb[base]), k2 = bf2f(kb[base + 32]);
  qb[base]      = valid ? f2bf(q1 * cs - q2 * sn) : (short)0;
  qb[base + 32] = valid ? f2bf(q2 * cs + q1 * sn) : (short)0;
  kb[base]      = valid ? f2bf(k1 * cs - k2 * sn) : (short)0;
  kb[base + 32] = valid ? f2bf(k2 * cs + k1 * sn) : (short)0;
  if (!valid) { vb[base] = 0; vb[base + 32] = 0; }
}

// ---------------- split-K flash attention with raw-barrier pipeline ----------------
// grid: (bh=128, split). Split s handles tiles kt = s, s+S, ... (strided).
// Per tile: ds_write(cur regs) -> issue next-tile loads -> lgkm+bar -> compute -> bar.
// Raw s_barrier (no vmcnt drain) keeps next-tile HBM loads in flight across compute.
__global__ __launch_bounds__(512) void attn_split(
    const float* __restrict__ pk, const float* __restrict__ pv,
    const short* __restrict__ qb, const short* __restrict__ kb,
    const short* __restrict__ vb, float* __restrict__ Opart,
    float* __restrict__ Ml, const int* __restrict__ past_len,
    const int* __restrict__ new_len, int splits)
{
  constexpr int LDT = 72;
  __shared__ short Kl[64 * LDT];    // [key][d]
  __shared__ short Vt[64 * LDT];    // [d][key ^ (d&56)] swizzled transpose
  __shared__ short Pl[128 * LDT];   // [q][key], per-wave private rows
  const int bh = blockIdx.x, b = bh >> 4, h = bh & 15;
  const int s = blockIdx.y;
  const int past = past_len[b];
  const int nlen = new_len[b];
  const int total = past + nlen;
  const int tid = threadIdx.x, lane = tid & 63, w = tid >> 6;
  const int lr = lane & 15, lk = lane >> 4;

  const int nt = (total + 63) >> 6;

  float* mlp = Ml + (size_t)(bh * splits + s) * 256;
  float* op  = Opart + (size_t)(bh * splits + s) * (128 * 64);

  if (s >= nt) {  // empty split: weight exp(-3e38-m*)==0 in combine
#pragma unroll
    for (int r = 0; r < 4; ++r) {
      const int q = w * 16 + lk * 4 + r;
      if (lr == 0) { mlp[q] = -3.0e38f; mlp[128 + q] = 0.f; }
    }
    return;
  }

  const bool wvalid = (w * 16) < nlen;  // wave-uniform: q rows >= nlen are don't-care
  short8 qf0 = {}, qf1 = {};
  if (wvalid) {
    const short* qrow = qb + (size_t)(b * 128 + w * 16 + lr) * DMODEL + h * 64;
    qf0 = *(const short8*)(qrow + lk * 8);
    qf1 = *(const short8*)(qrow + 32 + lk * 8);
  }
  float m_run[4], l_run[4];
  f32x4 acc[4] = {};
#pragma unroll
  for (int r = 0; r < 4; ++r) { m_run[r] = -3.0e38f; l_run[r] = 0.f; }

  const int jr = tid >> 3, seg = tid & 7;   // staging: key row jr, 8 d's per thread
  const float* pkb = pk + ((size_t)(b * 16 + h) * CMAX) * 64 + seg * 8;
  const float* pvb = pv + ((size_t)(b * 16 + h) * CMAX) * 64 + seg * 8;
  const short* kbb = kb + (size_t)(b * 128) * DMODEL + h * 64 + seg * 8;
  const short* vbb = vb + (size_t)(b * 128) * DMODEL + h * 64 + seg * 8;

  // two register staging sets (new-key short8 bitcast into the f32x4 slots)
  f32x4 kA0 = {}, kB0 = {}, vA0 = {}, vB0 = {};
  f32x4 kA1 = {}, kB1 = {}, vA1 = {}, vB1 = {};
  int smode0 = 2, smode1 = 2;

#define STAGE_ISSUE(SET, T)                                                   \
  {                                                                           \
    const int j_ = (T) * 64 + jr;                                             \
    if (j_ < past) {                                                          \
      smode##SET = 0;                                                         \
      kA##SET = *(const f32x4*)(pkb + (size_t)j_ * 64);                       \
      kB##SET = *(const f32x4*)(pkb + (size_t)j_ * 64 + 4);                   \
      vA##SET = *(const f32x4*)(pvb + (size_t)j_ * 64);                       \
      vB##SET = *(const f32x4*)(pvb + (size_t)j_ * 64 + 4);                   \
    } else if (j_ < total) {                                                  \
      smode##SET = 1;                                                         \
      kA##SET = __builtin_bit_cast(f32x4, *(const short8*)(kbb + (size_t)(j_ - past) * DMODEL)); \
      vA##SET = __builtin_bit_cast(f32x4, *(const short8*)(vbb + (size_t)(j_ - past) * DMODEL)); \
    } else {                                                                  \
      smode##SET = 2;                                                         \
    }                                                                         \
  }

#define ATTN_TILE(SET, OTHER, KT)                                             \
  {                                                                           \
    /* ---- LDS fill from set SET (compiler waits its vmcnt here) ---- */     \
    short8 kr = {}, vr = {};                                                  \
    if (smode##SET == 0) { kr = cvt8(kA##SET, kB##SET); vr = cvt8(vA##SET, vB##SET); } \
    else if (smode##SET == 1) { kr = __builtin_bit_cast(short8, kA##SET); vr = __builtin_bit_cast(short8, vA##SET); } \
    *(short8*)(Kl + jr * LDT + seg * 8) = kr;                                 \
    _Pragma("unroll")                                                         \
    for (int i = 0; i < 8; ++i) Vt[(seg * 8 + i) * LDT + (jr ^ (seg * 8))] = vr[i]; \
    /* ---- issue next tile's loads into the other set ---- */                \
    STAGE_ISSUE(OTHER, (KT) + splits);                                        \
    LGKM0_BAR();                                                              \
    if (wvalid) {                                                             \
      f32x4 sc[4];                                                            \
      __builtin_amdgcn_s_setprio(1);                                          \
      _Pragma("unroll")                                                       \
      for (int nf = 0; nf < 4; ++nf) {                                        \
        short8 k0 = *(const short8*)(Kl + (nf * 16 + lr) * LDT + lk * 8);     \
        short8 k1 = *(const short8*)(Kl + (nf * 16 + lr) * LDT + 32 + lk * 8);\
        f32x4 zv = {};                                                        \
        zv = __builtin_amdgcn_mfma_f32_16x16x32_bf16(qf0, k0, zv, 0, 0, 0);   \
        sc[nf] = __builtin_amdgcn_mfma_f32_16x16x32_bf16(qf1, k1, zv, 0, 0, 0);\
      }                                                                       \
      __builtin_amdgcn_s_setprio(0);                                          \
      const int kg0 = (KT) * 64;                                              \
      float pmax[4] = {-3.0e38f, -3.0e38f, -3.0e38f, -3.0e38f};               \
      _Pragma("unroll")                                                       \
      for (int nf = 0; nf < 4; ++nf) {                                        \
        const bool ok = (kg0 + nf * 16 + lr) < total;                         \
        _Pragma("unroll")                                                     \
        for (int r = 0; r < 4; ++r) {                                         \
          const float sv = ok ? sc[nf][r] * 0.125f : -3.0e38f;                \
          sc[nf][r] = sv;                                                     \
          pmax[r] = fmaxf(pmax[r], sv);                                       \
        }                                                                     \
      }                                                                       \
      _Pragma("unroll")                                                       \
      for (int r = 0; r < 4; ++r) {                                           \
        _Pragma("unroll")                                                     \
        for (int off = 1; off < 16; off <<= 1)                                \
          pmax[r] = fmaxf(pmax[r], __shfl_xor(pmax[r], off));                 \
      }                                                                       \
      float alpha[4], rsum[4];                                                \
      _Pragma("unroll")                                                       \
      for (int r = 0; r < 4; ++r) {                                           \
        const float mn = fmaxf(m_run[r], pmax[r]);                            \
        alpha[r] = __expf(m_run[r] - mn);                                     \
        m_run[r] = mn;                                                        \
        rsum[r] = 0.f;                                                        \
      }                                                                       \
      _Pragma("unroll")                                                       \
      for (int nf = 0; nf < 4; ++nf)                                          \
        _Pragma("unroll")                                                     \
        for (int r = 0; r < 4; ++r) {                                         \
          const float p = __expf(sc[nf][r] - m_run[r]);                       \
          sc[nf][r] = p;                                                      \
          rsum[r] += p;                                                       \
        }                                                                     \
      _Pragma("unroll")                                                       \
      for (int r = 0; r < 4; ++r) {                                           \
        _Pragma("unroll")                                                     \
        for (int off = 1; off < 16; off <<= 1)                                \
          rsum[r] += __shfl_xor(rsum[r], off);                                \
        l_run[r] = l_run[r] * alpha[r] + rsum[r];                             \
      }                                                                       \
      _Pragma("unroll")                                                       \
      for (int nf = 0; nf < 4; ++nf)                                          \
        _Pragma("unroll")                                                     \
        for (int r = 0; r < 4; ++r) acc[nf][r] *= alpha[r];                   \
      _Pragma("unroll")                                                       \
      for (int nf = 0; nf < 4; ++nf)                                          \
        _Pragma("unroll")                                                     \
        for (int r = 0; r < 4; ++r)                                           \
          Pl[(w * 16 + lk * 4 + r) * LDT + nf * 16 + lr] = f2bf(sc[nf][r]);   \
      __builtin_amdgcn_s_setprio(1);                                          \
      _Pragma("unroll")                                                       \
      for (int kf = 0; kf < 2; ++kf) {                                        \
        short8 pf = *(const short8*)(Pl + (w * 16 + lr) * LDT + kf * 32 + lk * 8); \
        _Pragma("unroll")                                                     \
        for (int nf = 0; nf < 4; ++nf) {                                      \
          const int dd = nf * 16 + lr;                                        \
          short8 vf = *(const short8*)(Vt + dd * LDT + ((kf * 32 + lk * 8) ^ (dd & 56))); \
          acc[nf] = __builtin_amdgcn_mfma_f32_16x16x32_bf16(pf, vf, acc[nf], 0, 0, 0); \
        }                                                                     \
      }                                                                       \
      __builtin_amdgcn_s_setprio(0);                                          \
    }                                                                         \
    TAIL_BAR();                                                               \
  }

  STAGE_ISSUE(0, s);
  const int nIter = (nt - s + splits - 1) / splits;
  const int E = (nIter + 1) & ~1;          // even trip; phantom tiles are fully masked
  for (int i = 0; i < E; i += 2) {
    const int kt0 = s + i * splits;
    ATTN_TILE(0, 1, kt0);
    ATTN_TILE(1, 0, kt0 + splits);
  }
#undef ATTN_TILE
#undef STAGE_ISSUE

  if (wvalid) {
#pragma unroll
    for (int nf = 0; nf < 4; ++nf)
#pragma unroll
      for (int r = 0; r < 4; ++r) {
        const int q = w * 16 + lk * 4 + r, d = nf * 16 + lr;
        op[(size_t)q * 64 + d] = acc[nf][r];
      }
#pragma unroll
    for (int r = 0; r < 4; ++r) {
      const int q = w * 16 + lk * 4 + r;
      if (lr == 0) { mlp[q] = m_run[r]; mlp[128 + q] = l_run[r]; }
    }
  } else {
#pragma unroll
    for (int r = 0; r < 4; ++r) {   // invalid q rows: mark zero-weight for combine
      const int q = w * 16 + lk * 4 + r;
      if (lr == 0) { mlp[q] = -3.0e38f; mlp[128 + q] = 0.f; }
    }
  }
}

// ---------------- combine partials -> ctx (bf16) ----------------
__global__ __launch_bounds__(256) void attn_combine(
    const float* __restrict__ Opart, const float* __restrict__ Ml,
    short* __restrict__ ctxb, const int* __restrict__ new_len, int splits)
{
  const int bh = blockIdx.x, b = bh >> 4, h = bh & 15;
  const int q = blockIdx.y * 16 + (threadIdx.x >> 4);
  if (q >= new_len[b]) return;  // ctx rows >= new_len are masked in the out-proj
  const int dv = (threadIdx.x & 15) * 4;
  const float* mlb = Ml + (size_t)bh * splits * 256;
  float mstar = -3.0e38f;
  for (int s = 0; s < splits; ++s)
    mstar = fmaxf(mstar, mlb[s * 256 + q]);
  float lsum = 0.f;
  f32x4 o = {};
  for (int s = 0; s < splits; ++s) {
    const float ws = __expf(mlb[s * 256 + q] - mstar);
    lsum += ws * mlb[s * 256 + 128 + q];
    if (ws > 0.f) {
      f32x4 ov = *(const f32x4*)(Opart + ((size_t)(bh * splits + s) * 128 + q) * 64 + dv);
      o.x += ws * ov.x; o.y += ws * ov.y; o.z += ws * ov.z; o.w += ws * ov.w;
    }
  }
  const float inv = 1.0f / lsum;
  short4v r;
  r.x = f2bf(o.x * inv); r.y = f2bf(o.y * inv); r.z = f2bf(o.z * inv); r.w = f2bf(o.w * inv);
  *(short4v*)(ctxb + (size_t)(b * 128 + q) * DMODEL + h * 64 + dv) = r;
}

// ---------------- launcher ----------------
extern "C" void kernel_launch(void* const* d_in, const int* in_sizes, int n_in,
                              void* d_out, int out_size, void* d_ws, size_t ws_size,
                              hipStream_t stream) {
  const float* x      = (const float*)d_in[0];
  const float* past_k = (const float*)d_in[1];
  const float* past_v = (const float*)d_in[2];
  const float* Wq = (const float*)d_in[3];
  const float* bq = (const float*)d_in[4];
  const float* Wk = (const float*)d_in[5];
  const float* bk = (const float*)d_in[6];
  const float* Wv = (const float*)d_in[7];
  const float* bv = (const float*)d_in[8];
  const float* Wo = (const float*)d_in[9];
  const float* bo = (const float*)d_in[10];
  const float* inv_freq = (const float*)d_in[11];
  const int* past_len = (const int*)d_in[12];
  const int* new_len  = (const int*)d_in[13];

  short* wsb = (short*)d_ws;
  const size_t M1 = 1u << 20;
  short* Xb  = wsb;
  short* Wqb = wsb + 1 * M1;
  short* Wob = wsb + 4 * M1;
  short* qb  = wsb + 5 * M1;
  short* kb  = wsb + 6 * M1;
  short* vb  = wsb + 7 * M1;
  short* ctx = wsb + 8 * M1;
  float* Opart = (float*)(wsb + 9 * M1);

  int splits = 1;
  for (int s = 8; s >= 1; s >>= 1) {
    size_t need = 9 * M1 * sizeof(short) +
                  (size_t)s * 128 * (128 * 64 + 256) * sizeof(float);
    if (need <= ws_size) { splits = s; break; }
  }
  float* Ml = Opart + (size_t)128 * splits * (128 * 64);

  cvt5_bf16<<<5120, 256, 0, stream>>>(x, Wq, Wk, Wv, Wo, wsb);

  gemm64<0><<<dim3(16, 16, 3), 256, 0, stream>>>(Xb, Wqb, (void*)qb, bq, bk, bv, new_len);
  rope_mask<<<2048, 256, 0, stream>>>(qb, kb, vb, inv_freq, past_len, new_len);
  attn_split<<<dim3(128, splits), 512, 0, stream>>>(past_k, past_v, qb, kb, vb,
                                                    Opart, Ml, past_len, new_len, splits);
  attn_combine<<<dim3(128, 8), 256, 0, stream>>>(Opart, Ml, ctx, new_len, splits);
  gemm64<1><<<dim3(16, 16, 1), 256, 0, stream>>>(ctx, Wob, d_out, bo, nullptr, nullptr, new_len);
}

// Round 9
// 75.608 us; speedup vs baseline: 1.0693x; 1.0693x over previous
//
#include <hip/hip_runtime.h>

#define NB 8
#define TNEW 128
#define CMAX 2048
#define DMODEL 1024
#define NH 16
#define DH 64

typedef float f32x4 __attribute__((ext_vector_type(4)));
typedef short short8 __attribute__((ext_vector_type(8)));
typedef short short4v __attribute__((ext_vector_type(4)));

__device__ __forceinline__ short f2bf(float x) {
  unsigned u = __float_as_uint(x);
  u += 0x7FFFu + ((u >> 16) & 1u);   // RTNE
  return (short)(u >> 16);
}
__device__ __forceinline__ float bf2f(short s) {
  return __uint_as_float(((unsigned)(unsigned short)s) << 16);
}
__device__ __forceinline__ short8 cvt8(f32x4 a, f32x4 b) {
  short8 o;
  o[0] = f2bf(a.x); o[1] = f2bf(a.y); o[2] = f2bf(a.z); o[3] = f2bf(a.w);
  o[4] = f2bf(b.x); o[5] = f2bf(b.y); o[6] = f2bf(b.z); o[7] = f2bf(b.w);
  return o;
}

#define LGKM0_BAR()                                            \
  __builtin_amdgcn_sched_barrier(0);                           \
  asm volatile("s_waitcnt lgkmcnt(0)" ::: "memory");           \
  __builtin_amdgcn_sched_barrier(0);                           \
  __builtin_amdgcn_s_barrier()
#define TAIL_BAR()                                             \
  __builtin_amdgcn_sched_barrier(0);                           \
  __builtin_amdgcn_s_barrier()

// ---------------- fused f32 -> bf16 convert: x, Wq, Wk, Wv, Wo ----------------
__global__ __launch_bounds__(256) void cvt5_bf16(
    const float* __restrict__ s0, const float* __restrict__ s1,
    const float* __restrict__ s2, const float* __restrict__ s3,
    const float* __restrict__ s4, short* __restrict__ dst) {
  const int seg = blockIdx.x >> 10;
  const int i = (blockIdx.x & 1023) * 256 + threadIdx.x;
  const float* src = seg == 0 ? s0 : seg == 1 ? s1 : seg == 2 ? s2 : seg == 3 ? s3 : s4;
  f32x4 v = *(const f32x4*)(src + (size_t)i * 4);
  short4v o;
  o.x = f2bf(v.x); o.y = f2bf(v.y); o.z = f2bf(v.z); o.w = f2bf(v.w);
  *(short4v*)(dst + (size_t)seg * (1u << 20) + (size_t)i * 4) = o;
}

// ---------------- GEMM: C[r,n] = sum_m A[r,m] * W[n,m] (+bias) ----------------
// Wave-column tiling gives each lane the (d, d+32) pair so RoPE (z<=1, MODE 0)
// is applied fully in-register in the epilogue. Raw-barrier K-loop pipeline.
template<int MODE>
__global__ __launch_bounds__(256) void gemm64(
    const short* __restrict__ A, const short* __restrict__ Wbase,
    void* __restrict__ Out, const float* __restrict__ bias0,
    const float* __restrict__ bias1, const float* __restrict__ bias2,
    const int* __restrict__ new_len, const float* __restrict__ inv_freq,
    const int* __restrict__ past_len)
{
  constexpr int LDT = 40;
  __shared__ short As[64 * LDT];
  __shared__ short Bs[64 * LDT];
  const int n0 = blockIdx.x * 64, m0 = blockIdx.y * 64, z = blockIdx.z;
  // q/k/v rows t >= new_len[b] are never consumed downstream.
  if (MODE == 0 && (m0 & 64) && new_len[m0 >> 7] <= 64) return;
  const short* Wp = Wbase + (size_t)z * (DMODEL * DMODEL);
  const float* bias = (MODE == 0) ? (z == 0 ? bias0 : (z == 1 ? bias1 : bias2)) : bias0;
  const int tid = threadIdx.x, lane = tid & 63, w = tid >> 6;
  const int wm = (w >> 1) * 32, wn2 = (w & 1) * 16;
  const int lr = lane & 15, lk = lane >> 4;

  const int srow = tid >> 2, soff = (tid & 3) * 8;
  const short* Ag = A  + (size_t)(m0 + srow) * DMODEL + soff;
  const short* Bg = Wp + (size_t)(n0 + srow) * DMODEL + soff;
  short* Al = As + srow * LDT + soff;
  short* Bl = Bs + srow * LDT + soff;

  short8 va0 = *(const short8*)(Ag);
  short8 vb0 = *(const short8*)(Bg);
  short8 va1, vb1;
  f32x4 acc[2][2] = {};   // [i: row-frag][j: col-frag at wn2 + j*32]

#define GEMM_PHASE(CURA, CURB, NXTA, NXTB, KNEXT)                          \
  {                                                                        \
    *(short8*)Al = CURA;                                                   \
    *(short8*)Bl = CURB;                                                   \
    NXTA = *(const short8*)(Ag + (KNEXT) * 32);                            \
    NXTB = *(const short8*)(Bg + (KNEXT) * 32);                            \
    LGKM0_BAR();                                                           \
    short8 af0 = *(const short8*)(As + (wm + lr) * LDT + lk * 8);          \
    short8 af1 = *(const short8*)(As + (wm + 16 + lr) * LDT + lk * 8);     \
    short8 bg0 = *(const short8*)(Bs + (wn2 + lr) * LDT + lk * 8);         \
    short8 bg1 = *(const short8*)(Bs + (wn2 + 32 + lr) * LDT + lk * 8);    \
    acc[0][0] = __builtin_amdgcn_mfma_f32_16x16x32_bf16(af0, bg0, acc[0][0], 0, 0, 0); \
    acc[0][1] = __builtin_amdgcn_mfma_f32_16x16x32_bf16(af0, bg1, acc[0][1], 0, 0, 0); \
    acc[1][0] = __builtin_amdgcn_mfma_f32_16x16x32_bf16(af1, bg0, acc[1][0], 0, 0, 0); \
    acc[1][1] = __builtin_amdgcn_mfma_f32_16x16x32_bf16(af1, bg1, acc[1][1], 0, 0, 0); \
    TAIL_BAR();                                                            \
  }

  for (int kt = 0; kt < DMODEL / 32; kt += 2) {
    const int k1 = kt + 1;
    const int k2 = (kt + 2 < DMODEL / 32) ? kt + 2 : DMODEL / 32 - 1;  // clamped, unused on last
    GEMM_PHASE(va0, vb0, va1, vb1, k1);
    GEMM_PHASE(va1, vb1, va0, vb0, k2);
  }
#undef GEMM_PHASE

  const int colb = n0 + wn2 + lr;          // j=0 col; j=1 col = colb + 32
  const float b0 = bias[colb], b1 = bias[colb + 32];

  if (MODE == 0 && z <= 1) {
    // fused RoPE: rows m0..m0+63 share b (m0 % 128 in {0,64})
    const int bb = m0 >> 7;
    const int pbase = past_len[bb];
    const float fr = inv_freq[(wn2 + lr) & 31];
    short* outp = (short*)Out + (size_t)z * (NB * TNEW * DMODEL);
#pragma unroll
    for (int i = 0; i < 2; ++i) {
#pragma unroll
      for (int r = 0; r < 4; ++r) {
        const int row = m0 + wm + i * 16 + lk * 4 + r;
        const float pos = (float)(pbase + (row & 127));
        float sn, cs;
        sincosf(pos * fr, &sn, &cs);
        const float a0 = acc[i][0][r] + b0;
        const float a1 = acc[i][1][r] + b1;
        outp[(size_t)row * DMODEL + colb]      = f2bf(a0 * cs - a1 * sn);
        outp[(size_t)row * DMODEL + colb + 32] = f2bf(a1 * cs + a0 * sn);
      }
    }
  } else {
#pragma unroll
    for (int i = 0; i < 2; ++i) {
#pragma unroll
      for (int r = 0; r < 4; ++r) {
        const int row = m0 + wm + i * 16 + lk * 4 + r;
        const float a0 = acc[i][0][r] + b0;
        const float a1 = acc[i][1][r] + b1;
        if (MODE == 0) {
          short* outp = (short*)Out + (size_t)z * (NB * TNEW * DMODEL);
          outp[(size_t)row * DMODEL + colb]      = f2bf(a0);
          outp[(size_t)row * DMODEL + colb + 32] = f2bf(a1);
        } else {
          const int bb = row >> 7, t = row & 127;
          const bool ok = t < new_len[bb];
          ((float*)Out)[(size_t)row * DMODEL + colb]      = ok ? a0 : 0.0f;
          ((float*)Out)[(size_t)row * DMODEL + colb + 32] = ok ? a1 : 0.0f;
        }
      }
    }
  }
}

// ---------------- split-K flash attention with raw-barrier pipeline ----------------
// 1-D grid, id -> (bh = id/splits, s = id%splits) so the ~4 blocks co-resident on a
// CU (id ≡ c mod 256) have bh differing by 32 — pole (b,h)'s splits spread across CUs.
__global__ __launch_bounds__(512) void attn_split(
    const float* __restrict__ pk, const float* __restrict__ pv,
    const short* __restrict__ qb, const short* __restrict__ kb,
    const short* __restrict__ vb, float* __restrict__ Opart,
    float* __restrict__ Ml, const int* __restrict__ past_len,
    const int* __restrict__ new_len, int splits)
{
  constexpr int LDT = 72;
  __shared__ short Kl[64 * LDT];    // [key][d]
  __shared__ short Vt[64 * LDT];    // [d][key ^ (d&56)] swizzled transpose
  __shared__ short Pl[128 * LDT];   // [q][key], per-wave private rows
  const int id = blockIdx.x;
  const int bh = id / splits, s = id - bh * splits;
  const int b = bh >> 4, h = bh & 15;
  const int past = past_len[b];
  const int nlen = new_len[b];
  const int total = past + nlen;
  const int tid = threadIdx.x, lane = tid & 63, w = tid >> 6;
  const int lr = lane & 15, lk = lane >> 4;

  const int nt = (total + 63) >> 6;

  float* mlp = Ml + (size_t)(bh * splits + s) * 256;
  float* op  = Opart + (size_t)(bh * splits + s) * (128 * 64);

  if (s >= nt) {  // empty split: weight exp(-3e38-m*)==0 in combine
#pragma unroll
    for (int r = 0; r < 4; ++r) {
      const int q = w * 16 + lk * 4 + r;
      if (lr == 0) { mlp[q] = -3.0e38f; mlp[128 + q] = 0.f; }
    }
    return;
  }

  const bool wvalid = (w * 16) < nlen;  // wave-uniform: q rows >= nlen are don't-care
  short8 qf0 = {}, qf1 = {};
  if (wvalid) {
    const short* qrow = qb + (size_t)(b * 128 + w * 16 + lr) * DMODEL + h * 64;
    qf0 = *(const short8*)(qrow + lk * 8);
    qf1 = *(const short8*)(qrow + 32 + lk * 8);
  }
  float m_run[4], l_run[4];
  f32x4 acc[4] = {};
#pragma unroll
  for (int r = 0; r < 4; ++r) { m_run[r] = -3.0e38f; l_run[r] = 0.f; }

  const int jr = tid >> 3, seg = tid & 7;   // staging: key row jr, 8 d's per thread
  const float* pkb = pk + ((size_t)(b * 16 + h) * CMAX) * 64 + seg * 8;
  const float* pvb = pv + ((size_t)(b * 16 + h) * CMAX) * 64 + seg * 8;
  const short* kbb = kb + (size_t)(b * 128) * DMODEL + h * 64 + seg * 8;
  const short* vbb = vb + (size_t)(b * 128) * DMODEL + h * 64 + seg * 8;

  // two register staging sets (new-key short8 bitcast into the f32x4 slots)
  f32x4 kA0 = {}, kB0 = {}, vA0 = {}, vB0 = {};
  f32x4 kA1 = {}, kB1 = {}, vA1 = {}, vB1 = {};
  int smode0 = 2, smode1 = 2;

#define STAGE_ISSUE(SET, T)                                                   \
  {                                                                           \
    const int j_ = (T) * 64 + jr;                                             \
    if (j_ < past) {                                                          \
      smode##SET = 0;                                                         \
      kA##SET = *(const f32x4*)(pkb + (size_t)j_ * 64);                       \
      kB##SET = *(const f32x4*)(pkb + (size_t)j_ * 64 + 4);                   \
      vA##SET = *(const f32x4*)(pvb + (size_t)j_ * 64);                       \
      vB##SET = *(const f32x4*)(pvb + (size_t)j_ * 64 + 4);                   \
    } else if (j_ < total) {                                                  \
      smode##SET = 1;                                                         \
      kA##SET = __builtin_bit_cast(f32x4, *(const short8*)(kbb + (size_t)(j_ - past) * DMODEL)); \
      vA##SET = __builtin_bit_cast(f32x4, *(const short8*)(vbb + (size_t)(j_ - past) * DMODEL)); \
    } else {                                                                  \
      smode##SET = 2;                                                         \
    }                                                                         \
  }

#define ATTN_TILE(SET, OTHER, KT)                                            \
  {                                                                           \
    /* ---- LDS fill from set SET (compiler waits its vmcnt here) ---- */     \
    short8 kr = {}, vr = {};                                                  \
    if (smode##SET == 0) { kr = cvt8(kA##SET, kB##SET); vr = cvt8(vA##SET, vB##SET); } \
    else if (smode##SET == 1) { kr = __builtin_bit_cast(short8, kA##SET); vr = __builtin_bit_cast(short8, vA##SET); } \
    *(short8*)(Kl + jr * LDT + seg * 8) = kr;                                 \
    _Pragma("unroll")                                                         \
    for (int i = 0; i < 8; ++i) Vt[(seg * 8 + i) * LDT + (jr ^ (seg * 8))] = vr[i]; \
    /* ---- issue next tile's loads into the other set ---- */                \
    STAGE_ISSUE(OTHER, (KT) + splits);                                        \
    LGKM0_BAR();                                                              \
    if (wvalid && (KT) < nt) {                                                \
      f32x4 sc[4];                                                            \
      __builtin_amdgcn_s_setprio(1);                                          \
      _Pragma("unroll")                                                       \
      for (int nf = 0; nf < 4; ++nf) {                                        \
        short8 k0 = *(const short8*)(Kl + (nf * 16 + lr) * LDT + lk * 8);     \
        short8 k1 = *(const short8*)(Kl + (nf * 16 + lr) * LDT + 32 + lk * 8);\
        f32x4 zv = {};                                                        \
        zv = __builtin_amdgcn_mfma_f32_16x16x32_bf16(qf0, k0, zv, 0, 0, 0);   \
        sc[nf] = __builtin_amdgcn_mfma_f32_16x16x32_bf16(qf1, k1, zv, 0, 0, 0);\
      }                                                                       \
      __builtin_amdgcn_s_setprio(0);                                          \
      const int kg0 = (KT) * 64;                                              \
      float pmax[4] = {-3.0e38f, -3.0e38f, -3.0e38f, -3.0e38f};               \
      _Pragma("unroll")                                                       \
      for (int nf = 0; nf < 4; ++nf) {                                        \
        const bool ok = (kg0 + nf * 16 + lr) < total;                         \
        _Pragma("unroll")                                                     \
        for (int r = 0; r < 4; ++r) {                                         \
          const float sv = ok ? sc[nf][r] * 0.125f : -3.0e38f;                \
          sc[nf][r] = sv;                                                     \
          pmax[r] = fmaxf(pmax[r], sv);                                       \
        }                                                                     \
      }                                                                       \
      _Pragma("unroll")                                                       \
      for (int r = 0; r < 4; ++r) {                                           \
        _Pragma("unroll")                                                     \
        for (int off = 1; off < 16; off <<= 1)                                \
          pmax[r] = fmaxf(pmax[r], __shfl_xor(pmax[r], off));                 \
      }                                                                       \
      float alpha[4], rsum[4];                                                \
      _Pragma("unroll")                                                       \
      for (int r = 0; r < 4; ++r) {                                           \
        const float mn = fmaxf(m_run[r], pmax[r]);                            \
        alpha[r] = __expf(m_run[r] - mn);                                     \
        m_run[r] = mn;                                                        \
        rsum[r] = 0.f;                                                        \
      }                                                                       \
      _Pragma("unroll")                                                       \
      for (int nf = 0; nf < 4; ++nf)                                          \
        _Pragma("unroll")                                                     \
        for (int r = 0; r < 4; ++r) {                                         \
          const float p = __expf(sc[nf][r] - m_run[r]);                       \
          sc[nf][r] = p;                                                      \
          rsum[r] += p;                                                       \
        }                                                                     \
      _Pragma("unroll")                                                       \
      for (int r = 0; r < 4; ++r) {                                           \
        _Pragma("unroll")                                                     \
        for (int off = 1; off < 16; off <<= 1)                                \
          rsum[r] += __shfl_xor(rsum[r], off);                                \
        l_run[r] = l_run[r] * alpha[r] + rsum[r];                             \
      }                                                                       \
      _Pragma("unroll")                                                       \
      for (int nf = 0; nf < 4; ++nf)                                          \
        _Pragma("unroll")                                                     \
        for (int r = 0; r < 4; ++r) acc[nf][r] *= alpha[r];                   \
      _Pragma("unroll")                                                       \
      for (int nf = 0; nf < 4; ++nf)                                          \
        _Pragma("unroll")                                                     \
        for (int r = 0; r < 4; ++r)                                           \
          Pl[(w * 16 + lk * 4 + r) * LDT + nf * 16 + lr] = f2bf(sc[nf][r]);   \
      __builtin_amdgcn_s_setprio(1);                                          \
      _Pragma("unroll")                                                       \
      for (int kf = 0; kf < 2; ++kf) {                                        \
        short8 pf = *(const short8*)(Pl + (w * 16 + lr) * LDT + kf * 32 + lk * 8); \
        _Pragma("unroll")                                                     \
        for (int nf = 0; nf < 4; ++nf) {                                      \
          const int dd = nf * 16 + lr;                                        \
          short8 vf = *(const short8*)(Vt + dd * LDT + ((kf * 32 + lk * 8) ^ (dd & 56))); \
          acc[nf] = __builtin_amdgcn_mfma_f32_16x16x32_bf16(pf, vf, acc[nf], 0, 0, 0); \
        }                                                                     \
      }                                                                       \
      __builtin_amdgcn_s_setprio(0);                                          \
    }                                                                         \
    TAIL_BAR();                                                               \
  }

  STAGE_ISSUE(0, s);
  const int nIter = (nt - s + splits - 1) / splits;
  const int E = (nIter + 1) & ~1;          // even trip; phantom tiles compute-skipped
  for (int i = 0; i < E; i += 2) {
    const int kt0 = s + i * splits;
    ATTN_TILE(0, 1, kt0);
    ATTN_TILE(1, 0, kt0 + splits);
  }
#undef ATTN_TILE
#undef STAGE_ISSUE

  if (wvalid) {
#pragma unroll
    for (int nf = 0; nf < 4; ++nf)
#pragma unroll
      for (int r = 0; r < 4; ++r) {
        const int q = w * 16 + lk * 4 + r, d = nf * 16 + lr;
        op[(size_t)q * 64 + d] = acc[nf][r];
      }
#pragma unroll
    for (int r = 0; r < 4; ++r) {
      const int q = w * 16 + lk * 4 + r;
      if (lr == 0) { mlp[q] = m_run[r]; mlp[128 + q] = l_run[r]; }
    }
  } else {
#pragma unroll
    for (int r = 0; r < 4; ++r) {   // invalid q rows: mark zero-weight for combine
      const int q = w * 16 + lk * 4 + r;
      if (lr == 0) { mlp[q] = -3.0e38f; mlp[128 + q] = 0.f; }
    }
  }
}

// ---------------- combine partials -> ctx (bf16) ----------------
__global__ __launch_bounds__(256) void attn_combine(
    const float* __restrict__ Opart, const float* __restrict__ Ml,
    short* __restrict__ ctxb, const int* __restrict__ new_len, int splits)
{
  const int bh = blockIdx.x, b = bh >> 4, h = bh & 15;
  const int q = blockIdx.y * 16 + (threadIdx.x >> 4);
  if (q >= new_len[b]) return;  // ctx rows >= new_len are masked in the out-proj
  const int dv = (threadIdx.x & 15) * 4;
  const float* mlb = Ml + (size_t)bh * splits * 256;
  float mstar = -3.0e38f;
  for (int s = 0; s < splits; ++s)
    mstar = fmaxf(mstar, mlb[s * 256 + q]);
  float lsum = 0.f;
  f32x4 o = {};
  for (int s = 0; s < splits; ++s) {
    const float ws = __expf(mlb[s * 256 + q] - mstar);
    lsum += ws * mlb[s * 256 + 128 + q];
    if (ws > 0.f) {
      f32x4 ov = *(const f32x4*)(Opart + ((size_t)(bh * splits + s) * 128 + q) * 64 + dv);
      o.x += ws * ov.x; o.y += ws * ov.y; o.z += ws * ov.z; o.w += ws * ov.w;
    }
  }
  const float inv = 1.0f / lsum;
  short4v r;
  r.x = f2bf(o.x * inv); r.y = f2bf(o.y * inv); r.z = f2bf(o.z * inv); r.w = f2bf(o.w * inv);
  *(short4v*)(ctxb + (size_t)(b * 128 + q) * DMODEL + h * 64 + dv) = r;
}

// ---------------- launcher ----------------
extern "C" void kernel_launch(void* const* d_in, const int* in_sizes, int n_in,
                              void* d_out, int out_size, void* d_ws, size_t ws_size,
                              hipStream_t stream) {
  const float* x      = (const float*)d_in[0];
  const float* past_k = (const float*)d_in[1];
  const float* past_v = (const float*)d_in[2];
  const float* Wq = (const float*)d_in[3];
  const float* bq = (const float*)d_in[4];
  const float* Wk = (const float*)d_in[5];
  const float* bk = (const float*)d_in[6];
  const float* Wv = (const float*)d_in[7];
  const float* bv = (const float*)d_in[8];
  const float* Wo = (const float*)d_in[9];
  const float* bo = (const float*)d_in[10];
  const float* inv_freq = (const float*)d_in[11];
  const int* past_len = (const int*)d_in[12];
  const int* new_len  = (const int*)d_in[13];

  short* wsb = (short*)d_ws;
  const size_t M1 = 1u << 20;
  short* Xb  = wsb;
  short* Wqb = wsb + 1 * M1;
  short* Wob = wsb + 4 * M1;
  short* qb  = wsb + 5 * M1;
  short* kb  = wsb + 6 * M1;
  short* vb  = wsb + 7 * M1;
  short* ctx = wsb + 8 * M1;
  float* Opart = (float*)(wsb + 9 * M1);

  int splits = 1;
  for (int s = 8; s >= 1; s >>= 1) {
    size_t need = 9 * M1 * sizeof(short) +
                  (size_t)s * 128 * (128 * 64 + 256) * sizeof(float);
    if (need <= ws_size) { splits = s; break; }
  }
  float* Ml = Opart + (size_t)128 * splits * (128 * 64);

  cvt5_bf16<<<5120, 256, 0, stream>>>(x, Wq, Wk, Wv, Wo, wsb);

  gemm64<0><<<dim3(16, 16, 3), 256, 0, stream>>>(Xb, Wqb, (void*)qb, bq, bk, bv,
                                                 new_len, inv_freq, past_len);
  attn_split<<<128 * splits, 512, 0, stream>>>(past_k, past_v, qb, kb, vb,
                                               Opart, Ml, past_len, new_len, splits);
  attn_combine<<<dim3(128, 8), 256, 0, stream>>>(Opart, Ml, ctx, new_len, splits);
  gemm64<1><<<dim3(16, 16, 1), 256, 0, stream>>>(ctx, Wob, d_out, bo, nullptr, nullptr,
                                                 new_len, nullptr, nullptr);
}

// Round 10
// 67.655 us; speedup vs baseline: 1.1950x; 1.1176x over previous
//
#include <hip/hip_runtime.h>

#define NB 8
#define TNEW 128
#define CMAX 2048
#define DMODEL 1024
#define NH 16
#define DH 64

typedef float f32x4 __attribute__((ext_vector_type(4)));
typedef short short8 __attribute__((ext_vector_type(8)));
typedef short short4v __attribute__((ext_vector_type(4)));
typedef unsigned uint4v __attribute__((ext_vector_type(4)));

__device__ __forceinline__ short f2bf(float x) {
  unsigned u = __float_as_uint(x);
  u += 0x7FFFu + ((u >> 16) & 1u);   // RTNE
  return (short)(u >> 16);
}
__device__ __forceinline__ float bf2f(short s) {
  return __uint_as_float(((unsigned)(unsigned short)s) << 16);
}
// 8 f32 -> 8 bf16 via v_cvt_pk_bf16_f32 (one VALU op per pair, RNE)
__device__ __forceinline__ short8 cvt8(f32x4 a, f32x4 b) {
  uint4v t;
  asm("v_cvt_pk_bf16_f32 %0, %1, %2" : "=v"(t.x) : "v"(a.x), "v"(a.y));
  asm("v_cvt_pk_bf16_f32 %0, %1, %2" : "=v"(t.y) : "v"(a.z), "v"(a.w));
  asm("v_cvt_pk_bf16_f32 %0, %1, %2" : "=v"(t.z) : "v"(b.x), "v"(b.y));
  asm("v_cvt_pk_bf16_f32 %0, %1, %2" : "=v"(t.w) : "v"(b.z), "v"(b.w));
  return __builtin_bit_cast(short8, t);
}

#define LGKM0_BAR()                                            \
  __builtin_amdgcn_sched_barrier(0);                           \
  asm volatile("s_waitcnt lgkmcnt(0)" ::: "memory");           \
  __builtin_amdgcn_sched_barrier(0);                           \
  __builtin_amdgcn_s_barrier()
#define TAIL_BAR()                                             \
  __builtin_amdgcn_sched_barrier(0);                           \
  __builtin_amdgcn_s_barrier()

// ---------------- fused f32 -> bf16 convert: x, Wq, Wk, Wv, Wo ----------------
__global__ __launch_bounds__(256) void cvt5_bf16(
    const float* __restrict__ s0, const float* __restrict__ s1,
    const float* __restrict__ s2, const float* __restrict__ s3,
    const float* __restrict__ s4, short* __restrict__ dst) {
  const int seg = blockIdx.x >> 10;
  const int i = (blockIdx.x & 1023) * 256 + threadIdx.x;
  const float* src = seg == 0 ? s0 : seg == 1 ? s1 : seg == 2 ? s2 : seg == 3 ? s3 : s4;
  f32x4 v = *(const f32x4*)(src + (size_t)i * 4);
  short4v o;
  o.x = f2bf(v.x); o.y = f2bf(v.y); o.z = f2bf(v.z); o.w = f2bf(v.w);
  *(short4v*)(dst + (size_t)seg * (1u << 20) + (size_t)i * 4) = o;
}

// ---------------- GEMM: C[r,n] = sum_m A[r,m] * W[n,m] (+bias) ----------------
// Wave-column tiling gives each lane the (d, d+32) pair so RoPE (z<=1, MODE 0)
// is applied fully in-register in the epilogue. Raw-barrier K-loop pipeline.
template<int MODE>
__global__ __launch_bounds__(256) void gemm64(
    const short* __restrict__ A, const short* __restrict__ Wbase,
    void* __restrict__ Out, const float* __restrict__ bias0,
    const float* __restrict__ bias1, const float* __restrict__ bias2,
    const int* __restrict__ new_len, const float* __restrict__ inv_freq,
    const int* __restrict__ past_len)
{
  constexpr int LDT = 40;
  __shared__ short As[64 * LDT];
  __shared__ short Bs[64 * LDT];
  const int n0 = blockIdx.x * 64, m0 = blockIdx.y * 64, z = blockIdx.z;
  // q/k/v rows t >= new_len[b] are never consumed downstream.
  if (MODE == 0 && (m0 & 64) && new_len[m0 >> 7] <= 64) return;
  const short* Wp = Wbase + (size_t)z * (DMODEL * DMODEL);
  const float* bias = (MODE == 0) ? (z == 0 ? bias0 : (z == 1 ? bias1 : bias2)) : bias0;
  const int tid = threadIdx.x, lane = tid & 63, w = tid >> 6;
  const int wm = (w >> 1) * 32, wn2 = (w & 1) * 16;
  const int lr = lane & 15, lk = lane >> 4;

  const int srow = tid >> 2, soff = (tid & 3) * 8;
  const short* Ag = A  + (size_t)(m0 + srow) * DMODEL + soff;
  const short* Bg = Wp + (size_t)(n0 + srow) * DMODEL + soff;
  short* Al = As + srow * LDT + soff;
  short* Bl = Bs + srow * LDT + soff;

  short8 va0 = *(const short8*)(Ag);
  short8 vb0 = *(const short8*)(Bg);
  short8 va1, vb1;
  f32x4 acc[2][2] = {};   // [i: row-frag][j: col-frag at wn2 + j*32]

#define GEMM_PHASE(CURA, CURB, NXTA, NXTB, KNEXT)                          \
  {                                                                        \
    *(short8*)Al = CURA;                                                   \
    *(short8*)Bl = CURB;                                                   \
    NXTA = *(const short8*)(Ag + (KNEXT) * 32);                            \
    NXTB = *(const short8*)(Bg + (KNEXT) * 32);                            \
    LGKM0_BAR();                                                           \
    short8 af0 = *(const short8*)(As + (wm + lr) * LDT + lk * 8);          \
    short8 af1 = *(const short8*)(As + (wm + 16 + lr) * LDT + lk * 8);     \
    short8 bg0 = *(const short8*)(Bs + (wn2 + lr) * LDT + lk * 8);         \
    short8 bg1 = *(const short8*)(Bs + (wn2 + 32 + lr) * LDT + lk * 8);    \
    acc[0][0] = __builtin_amdgcn_mfma_f32_16x16x32_bf16(af0, bg0, acc[0][0], 0, 0, 0); \
    acc[0][1] = __builtin_amdgcn_mfma_f32_16x16x32_bf16(af0, bg1, acc[0][1], 0, 0, 0); \
    acc[1][0] = __builtin_amdgcn_mfma_f32_16x16x32_bf16(af1, bg0, acc[1][0], 0, 0, 0); \
    acc[1][1] = __builtin_amdgcn_mfma_f32_16x16x32_bf16(af1, bg1, acc[1][1], 0, 0, 0); \
    TAIL_BAR();                                                            \
  }

  for (int kt = 0; kt < DMODEL / 32; kt += 2) {
    const int k1 = kt + 1;
    const int k2 = (kt + 2 < DMODEL / 32) ? kt + 2 : DMODEL / 32 - 1;  // clamped, unused on last
    GEMM_PHASE(va0, vb0, va1, vb1, k1);
    GEMM_PHASE(va1, vb1, va0, vb0, k2);
  }
#undef GEMM_PHASE

  const int colb = n0 + wn2 + lr;          // j=0 col; j=1 col = colb + 32
  const float b0 = bias[colb], b1 = bias[colb + 32];

  if (MODE == 0 && z <= 1) {
    // fused RoPE: rows m0..m0+63 share b (m0 % 128 in {0,64})
    const int bb = m0 >> 7;
    const int pbase = past_len[bb];
    const float fr = inv_freq[(wn2 + lr) & 31];
    short* outp = (short*)Out + (size_t)z * (NB * TNEW * DMODEL);
#pragma unroll
    for (int i = 0; i < 2; ++i) {
#pragma unroll
      for (int r = 0; r < 4; ++r) {
        const int row = m0 + wm + i * 16 + lk * 4 + r;
        const float pos = (float)(pbase + (row & 127));
        float sn, cs;
        sincosf(pos * fr, &sn, &cs);
        const float a0 = acc[i][0][r] + b0;
        const float a1 = acc[i][1][r] + b1;
        outp[(size_t)row * DMODEL + colb]      = f2bf(a0 * cs - a1 * sn);
        outp[(size_t)row * DMODEL + colb + 32] = f2bf(a1 * cs + a0 * sn);
      }
    }
  } else {
#pragma unroll
    for (int i = 0; i < 2; ++i) {
#pragma unroll
      for (int r = 0; r < 4; ++r) {
        const int row = m0 + wm + i * 16 + lk * 4 + r;
        const float a0 = acc[i][0][r] + b0;
        const float a1 = acc[i][1][r] + b1;
        if (MODE == 0) {
          short* outp = (short*)Out + (size_t)z * (NB * TNEW * DMODEL);
          outp[(size_t)row * DMODEL + colb]      = f2bf(a0);
          outp[(size_t)row * DMODEL + colb + 32] = f2bf(a1);
        } else {
          const int bb = row >> 7, t = row & 127;
          const bool ok = t < new_len[bb];
          ((float*)Out)[(size_t)row * DMODEL + colb]      = ok ? a0 : 0.0f;
          ((float*)Out)[(size_t)row * DMODEL + colb + 32] = ok ? a1 : 0.0f;
        }
      }
    }
  }
}

// ---------------- split-K flash attention, spill-free single-set pipeline ----------------
// grid 1-D: id -> (bh = id/splits, s = id%splits). Split s takes tiles s, s+S, ...
// Per tile: select+LDS-fill(regs) -> issue clamped dual loads(t+S) -> lgkm+bar ->
// compute -> bar. ONE staging set (ds_write reads regs at issue; reload is WAR-safe).
// Dual-load (f32 past + bf16 new, both always, clamped addresses) kills the branchy
// register demotion that was spilling to scratch in rounds 2-9.
__global__ __launch_bounds__(512, 4) void attn_split(
    const float* __restrict__ pk, const float* __restrict__ pv,
    const short* __restrict__ qb, const short* __restrict__ kb,
    const short* __restrict__ vb, float* __restrict__ Opart,
    float* __restrict__ Ml, const int* __restrict__ past_len,
    const int* __restrict__ new_len, int splits)
{
  constexpr int LDT = 72;
  __shared__ short Kl[64 * LDT];    // [key][d]
  __shared__ short Vt[64 * LDT];    // [d][key ^ (d&56)] swizzled transpose
  __shared__ short Pl[128 * LDT];   // [q][key], per-wave private rows
  const int id = blockIdx.x;
  const int bh = id / splits, s = id - bh * splits;
  const int b = bh >> 4, h = bh & 15;
  const int past = past_len[b];
  const int nlen = new_len[b];
  const int total = past + nlen;
  const int tid = threadIdx.x, lane = tid & 63, w = tid >> 6;
  const int lr = lane & 15, lk = lane >> 4;

  const int nt = (total + 63) >> 6;

  float* mlp = Ml + (size_t)(bh * splits + s) * 256;
  float* op  = Opart + (size_t)(bh * splits + s) * (128 * 64);

  if (s >= nt) {  // empty split: weight exp(-3e38-m*)==0 in combine
#pragma unroll
    for (int r = 0; r < 4; ++r) {
      const int q = w * 16 + lk * 4 + r;
      if (lr == 0) { mlp[q] = -3.0e38f; mlp[128 + q] = 0.f; }
    }
    return;
  }

  const bool wvalid = (w * 16) < nlen;  // wave-uniform: q rows >= nlen are don't-care
  short8 qf0 = {}, qf1 = {};
  if (wvalid) {
    const short* qrow = qb + (size_t)(b * 128 + w * 16 + lr) * DMODEL + h * 64;
    qf0 = *(const short8*)(qrow + lk * 8);
    qf1 = *(const short8*)(qrow + 32 + lk * 8);
  }
  float m_run[4], l_run[4];
  f32x4 acc[4] = {};
#pragma unroll
  for (int r = 0; r < 4; ++r) { m_run[r] = -3.0e38f; l_run[r] = 0.f; }

  const int jr = tid >> 3, seg = tid & 7;   // staging: key row jr, 8 d's per thread
  const float* pkb = pk + ((size_t)(b * 16 + h) * CMAX) * 64 + seg * 8;
  const float* pvb = pv + ((size_t)(b * 16 + h) * CMAX) * 64 + seg * 8;
  const short* kbb = kb + (size_t)(b * 128) * DMODEL + h * 64 + seg * 8;
  const short* vbb = vb + (size_t)(b * 128) * DMODEL + h * 64 + seg * 8;

  // single staging set: f32 candidates (16 regs) + bf16 candidates (8 regs) + 2 preds
  f32x4 kF0, kF1, vF0, vF1;
  short8 kN, vN;
  bool pr0, pr1;

#define STAGE_ISSUE(T)                                                        \
  {                                                                           \
    const int j_ = (T) * 64 + jr;                                             \
    const int jp = min(j_, past - 1);            /* past >= 1 always */       \
    const int jn = min(max(j_ - past, 0), TNEW - 1);                          \
    pr0 = j_ < past;                                                          \
    pr1 = j_ < total;                                                         \
    kF0 = *(const f32x4*)(pkb + (size_t)jp * 64);                             \
    kF1 = *(const f32x4*)(pkb + (size_t)jp * 64 + 4);                         \
    vF0 = *(const f32x4*)(pvb + (size_t)jp * 64);                             \
    vF1 = *(const f32x4*)(pvb + (size_t)jp * 64 + 4);                         \
    kN  = *(const short8*)(kbb + (size_t)jn * DMODEL);                        \
    vN  = *(const short8*)(vbb + (size_t)jn * DMODEL);                        \
  }

  STAGE_ISSUE(s);
  for (int kt = s; kt < nt; kt += splits) {
    // ---- LDS fill: branchless select of staged candidates ----
    {
      const short8 z8 = {};
      short8 kc = cvt8(kF0, kF1);
      short8 vc = cvt8(vF0, vF1);
      short8 kr = pr0 ? kc : (pr1 ? kN : z8);
      short8 vr = pr0 ? vc : (pr1 ? vN : z8);
      *(short8*)(Kl + jr * LDT + seg * 8) = kr;
#pragma unroll
      for (int i = 0; i < 8; ++i) Vt[(seg * 8 + i) * LDT + (jr ^ (seg * 8))] = vr[i];
    }
    // ---- issue next tile's loads (clamped => always safe); fly across compute ----
    STAGE_ISSUE(kt + splits);
    LGKM0_BAR();

    if (wvalid) {
      f32x4 sc[4];
      __builtin_amdgcn_s_setprio(1);
#pragma unroll
      for (int nf = 0; nf < 4; ++nf) {
        short8 k0 = *(const short8*)(Kl + (nf * 16 + lr) * LDT + lk * 8);
        short8 k1 = *(const short8*)(Kl + (nf * 16 + lr) * LDT + 32 + lk * 8);
        f32x4 zv = {};
        zv = __builtin_amdgcn_mfma_f32_16x16x32_bf16(qf0, k0, zv, 0, 0, 0);
        sc[nf] = __builtin_amdgcn_mfma_f32_16x16x32_bf16(qf1, k1, zv, 0, 0, 0);
      }
      __builtin_amdgcn_s_setprio(0);
      const int kg0 = kt * 64;
      float pmax[4] = {-3.0e38f, -3.0e38f, -3.0e38f, -3.0e38f};
#pragma unroll
      for (int nf = 0; nf < 4; ++nf) {
        const bool ok = (kg0 + nf * 16 + lr) < total;
#pragma unroll
        for (int r = 0; r < 4; ++r) {
          const float sv = ok ? sc[nf][r] * 0.125f : -3.0e38f;
          sc[nf][r] = sv;
          pmax[r] = fmaxf(pmax[r], sv);
        }
      }
#pragma unroll
      for (int r = 0; r < 4; ++r) {
#pragma unroll
        for (int off = 1; off < 16; off <<= 1)
          pmax[r] = fmaxf(pmax[r], __shfl_xor(pmax[r], off));
      }
      float alpha[4], rsum[4];
#pragma unroll
      for (int r = 0; r < 4; ++r) {
        const float mn = fmaxf(m_run[r], pmax[r]);
        alpha[r] = __expf(m_run[r] - mn);
        m_run[r] = mn;
        rsum[r] = 0.f;
      }
#pragma unroll
      for (int nf = 0; nf < 4; ++nf)
#pragma unroll
        for (int r = 0; r < 4; ++r) {
          const float p = __expf(sc[nf][r] - m_run[r]);
          sc[nf][r] = p;
          rsum[r] += p;
        }
#pragma unroll
      for (int r = 0; r < 4; ++r) {
#pragma unroll
        for (int off = 1; off < 16; off <<= 1)
          rsum[r] += __shfl_xor(rsum[r], off);
        l_run[r] = l_run[r] * alpha[r] + rsum[r];
      }
#pragma unroll
      for (int nf = 0; nf < 4; ++nf)
#pragma unroll
        for (int r = 0; r < 4; ++r) acc[nf][r] *= alpha[r];

      // P -> LDS (C-layout rows), then PV MFMAs (same-wave RAW: in-order DS)
#pragma unroll
      for (int nf = 0; nf < 4; ++nf)
#pragma unroll
        for (int r = 0; r < 4; ++r)
          Pl[(w * 16 + lk * 4 + r) * LDT + nf * 16 + lr] = f2bf(sc[nf][r]);
      __builtin_amdgcn_s_setprio(1);
#pragma unroll
      for (int kf = 0; kf < 2; ++kf) {
        short8 pf = *(const short8*)(Pl + (w * 16 + lr) * LDT + kf * 32 + lk * 8);
#pragma unroll
        for (int nf = 0; nf < 4; ++nf) {
          const int dd = nf * 16 + lr;
          short8 vf = *(const short8*)(Vt + dd * LDT + ((kf * 32 + lk * 8) ^ (dd & 56)));
          acc[nf] = __builtin_amdgcn_mfma_f32_16x16x32_bf16(pf, vf, acc[nf], 0, 0, 0);
        }
      }
      __builtin_amdgcn_s_setprio(0);
    }
    TAIL_BAR();
  }
#undef STAGE_ISSUE

  if (wvalid) {
#pragma unroll
    for (int nf = 0; nf < 4; ++nf)
#pragma unroll
      for (int r = 0; r < 4; ++r) {
        const int q = w * 16 + lk * 4 + r, d = nf * 16 + lr;
        op[(size_t)q * 64 + d] = acc[nf][r];
      }
#pragma unroll
    for (int r = 0; r < 4; ++r) {
      const int q = w * 16 + lk * 4 + r;
      if (lr == 0) { mlp[q] = m_run[r]; mlp[128 + q] = l_run[r]; }
    }
  } else {
#pragma unroll
    for (int r = 0; r < 4; ++r) {   // invalid q rows: mark zero-weight for combine
      const int q = w * 16 + lk * 4 + r;
      if (lr == 0) { mlp[q] = -3.0e38f; mlp[128 + q] = 0.f; }
    }
  }
}

// ---------------- combine partials -> ctx (bf16) ----------------
__global__ __launch_bounds__(256) void attn_combine(
    const float* __restrict__ Opart, const float* __restrict__ Ml,
    short* __restrict__ ctxb, const int* __restrict__ new_len, int splits)
{
  const int bh = blockIdx.x, b = bh >> 4, h = bh & 15;
  const int q = blockIdx.y * 16 + (threadIdx.x >> 4);
  if (q >= new_len[b]) return;  // ctx rows >= new_len are masked in the out-proj
  const int dv = (threadIdx.x & 15) * 4;
  const float* mlb = Ml + (size_t)bh * splits * 256;
  float mstar = -3.0e38f;
  for (int s = 0; s < splits; ++s)
    mstar = fmaxf(mstar, mlb[s * 256 + q]);
  float lsum = 0.f;
  f32x4 o = {};
  for (int s = 0; s < splits; ++s) {
    const float ws = __expf(mlb[s * 256 + q] - mstar);
    lsum += ws * mlb[s * 256 + 128 + q];
    if (ws > 0.f) {
      f32x4 ov = *(const f32x4*)(Opart + ((size_t)(bh * splits + s) * 128 + q) * 64 + dv);
      o.x += ws * ov.x; o.y += ws * ov.y; o.z += ws * ov.z; o.w += ws * ov.w;
    }
  }
  const float inv = 1.0f / lsum;
  short4v r;
  r.x = f2bf(o.x * inv); r.y = f2bf(o.y * inv); r.z = f2bf(o.z * inv); r.w = f2bf(o.w * inv);
  *(short4v*)(ctxb + (size_t)(b * 128 + q) * DMODEL + h * 64 + dv) = r;
}

// ---------------- launcher ----------------
extern "C" void kernel_launch(void* const* d_in, const int* in_sizes, int n_in,
                              void* d_out, int out_size, void* d_ws, size_t ws_size,
                              hipStream_t stream) {
  const float* x      = (const float*)d_in[0];
  const float* past_k = (const float*)d_in[1];
  const float* past_v = (const float*)d_in[2];
  const float* Wq = (const float*)d_in[3];
  const float* bq = (const float*)d_in[4];
  const float* Wk = (const float*)d_in[5];
  const float* bk = (const float*)d_in[6];
  const float* Wv = (const float*)d_in[7];
  const float* bv = (const float*)d_in[8];
  const float* Wo = (const float*)d_in[9];
  const float* bo = (const float*)d_in[10];
  const float* inv_freq = (const float*)d_in[11];
  const int* past_len = (const int*)d_in[12];
  const int* new_len  = (const int*)d_in[13];

  short* wsb = (short*)d_ws;
  const size_t M1 = 1u << 20;
  short* Xb  = wsb;
  short* Wqb = wsb + 1 * M1;
  short* Wob = wsb + 4 * M1;
  short* qb  = wsb + 5 * M1;
  short* kb  = wsb + 6 * M1;
  short* vb  = wsb + 7 * M1;
  short* ctx = wsb + 8 * M1;
  float* Opart = (float*)(wsb + 9 * M1);

  int splits = 1;
  for (int s = 8; s >= 1; s >>= 1) {
    size_t need = 9 * M1 * sizeof(short) +
                  (size_t)s * 128 * (128 * 64 + 256) * sizeof(float);
    if (need <= ws_size) { splits = s; break; }
  }
  float* Ml = Opart + (size_t)128 * splits * (128 * 64);

  cvt5_bf16<<<5120, 256, 0, stream>>>(x, Wq, Wk, Wv, Wo, wsb);

  gemm64<0><<<dim3(16, 16, 3), 256, 0, stream>>>(Xb, Wqb, (void*)qb, bq, bk, bv,
                                                 new_len, inv_freq, past_len);
  attn_split<<<128 * splits, 512, 0, stream>>>(past_k, past_v, qb, kb, vb,
                                               Opart, Ml, past_len, new_len, splits);
  attn_combine<<<dim3(128, 8), 256, 0, stream>>>(Opart, Ml, ctx, new_len, splits);
  gemm64<1><<<dim3(16, 16, 1), 256, 0, stream>>>(ctx, Wob, d_out, bo, nullptr, nullptr,
                                                 new_len, nullptr, nullptr);
}